// Round 19
// baseline (47.781 us; speedup 1.0000x reference)
//
#include <hip/hip_runtime.h>
#include <math.h>

#define CCH     128
#define HWTOK   4096
#define MROWS   512
#define THREADS 1024   // main: 16 waves; 256 blocks = 1 block/CU

using float16 = __attribute__((ext_vector_type(16))) float;
using f4      = __attribute__((ext_vector_type(4))) float;
using f2      = __attribute__((ext_vector_type(2))) float;
using i4      = __attribute__((ext_vector_type(4))) int;

__device__ __forceinline__ float fmax3(float a, float b, float c) {
    return fmaxf(fmaxf(a, b), c);   // clang fuses to v_max3_f32
}

// pack 8 f32 -> 8 fp8 e4m3 (OCP) bytes in ascending order, via HW cvt
__device__ __forceinline__ long pack_fp8x8(const float* v) {
    int w0 = 0, w1 = 0;
    w0 = __builtin_amdgcn_cvt_pk_fp8_f32(v[0], v[1], w0, false);
    w0 = __builtin_amdgcn_cvt_pk_fp8_f32(v[2], v[3], w0, true);
    w1 = __builtin_amdgcn_cvt_pk_fp8_f32(v[4], v[5], w1, false);
    w1 = __builtin_amdgcn_cvt_pk_fp8_f32(v[6], v[7], w1, true);
    return (long)(unsigned)w0 | ((long)w1 << 32);
}

// ---------------------------------------------------------------------------
// Fill: dedicated pure-write zero-fill of `out`, byte-identical shape to the
// runtime's fillBufferAligned (grid-stride f4) — measured 6.7 TB/s, 1.00x
// WRITE_SIZE on this chip. Keeping it a PURE write stream is the experiment:
// every kernel that interleaved reads+writes ran at <=2.5 TB/s effective.
// ---------------------------------------------------------------------------
__global__ __launch_bounds__(256) void fill_kernel(float* __restrict__ out) {
    f4* o = reinterpret_cast<f4*>(out);
    int idx = blockIdx.x * 256 + threadIdx.x;
    f4 z = {0.f, 0.f, 0.f, 0.f};
    #pragma unroll
    for (int i = 0; i < 8; ++i)
        o[idx + i * (2048 * 256)] = z;
}

// ---------------------------------------------------------------------------
// Prep: pre-normalized memory rows as fp8 e4m3 MFMA A-fragments (64 KB table).
// fid = (mt*8 + kstep)*64 + lane, lane = hi*32 + r5 holds
//   fp8(memory[mt*32 + r5][kstep*16 + hi*8 + j] * rinv(row)), j = 0..7.
// ---------------------------------------------------------------------------
__global__ __launch_bounds__(256) void frag_kernel(const float* __restrict__ mem,
                                                   long* __restrict__ wsfrag) {
    int fid   = blockIdx.x * 256 + threadIdx.x;   // 0..8191
    int mt    = fid >> 9;
    int rem   = fid & 511;
    int kstep = rem >> 6;
    int l     = rem & 63;
    int hi    = l >> 5, r5 = l & 31;
    int row   = mt * 32 + r5;
    int k0    = kstep * 16 + hi * 8;

    const float* mr = mem + (size_t)row * CCH;
    float s = 0.f;
    #pragma unroll
    for (int c = 0; c < CCH; c += 4) {
        f4 v = *reinterpret_cast<const f4*>(mr + c);
        s += v.x * v.x + v.y * v.y + v.z * v.z + v.w * v.w;
    }
    float sc = 1.0f / fmaxf(sqrtf(s), 1e-12f);

    float v[8];
    #pragma unroll
    for (int j = 0; j < 8; ++j) v[j] = mr[k0 + j] * sc;
    wsfrag[fid] = pack_fp8x8(v);
}

// ---------------------------------------------------------------------------
// Main: r18 kernel with the fused fill REMOVED (single-variable experiment:
// separate pure-write fill vs fused). Now a pure-read+compute kernel:
// storage-linear x reads (1 KB contiguous/instr), f32->fp8 cvt in flight,
// 64 KB LDS x tile [c][t] + 64 KB fp8 row table; one barrier; max-only fp8
// MFMA hot loop; common (no-hit) case stores NOTHING (zeros pre-filled);
// ballot-guarded exact argmax recompute for rare hits.
// ---------------------------------------------------------------------------
__global__ __launch_bounds__(THREADS) void hardmem_mfma(
    const float* __restrict__ x, const float* __restrict__ mem,
    const long* __restrict__ wsfrag, float* __restrict__ out)
{
    __shared__ long sfrag[8192];            // 64 KB — fp8 row-fragment table
    __shared__ unsigned char xs8[65536];    // 64 KB — fp8 x tile [c][t], t=0..511

    const int tid  = threadIdx.x;
    const int wid  = tid >> 6;                 // 0..15
    const int lane = tid & 63;
    const int l5   = lane & 31, hi = lane >> 5;

    const int b    = blockIdx.x >> 3;                    // 8 blocks/batch
    const int treg = (blockIdx.x & 7) * 512;             // block token region
    const float* xb = x + (size_t)b * CCH * HWTOK + treg;
    float* obase    = out + (size_t)b * CCH * HWTOK;

    // ---- 1. stage fp8 row table -> LDS (64 KB, L2-hot)
    {
        const i4* wsv = reinterpret_cast<const i4*>(wsfrag);
        i4* sfv = reinterpret_cast<i4*>(sfrag);
        #pragma unroll
        for (int i = 0; i < 4; ++i) {
            int idx = tid + i * THREADS;       // 0..4095 i4s
            sfv[idx] = wsv[idx];
        }
    }

    // ---- 2. stage x -> fp8 LDS tile, STORAGE-LINEAR reads.
    // idx = c*128 + o: lane-consecutive o -> 64 lanes x 16B = 1 KB contiguous
    // per instruction. cvt f32->fp8 in flight; ds_write_b32 2 lanes/bank=free.
    {
        unsigned* xsu = reinterpret_cast<unsigned*>(xs8);
        #pragma unroll
        for (int i = 0; i < 16; ++i) {
            int idx = tid + i * THREADS;       // 0..16383
            int c = idx >> 7, o = idx & 127;   // channel, f4-offset (4 tokens)
            f4 v = *reinterpret_cast<const f4*>(xb + (size_t)c * HWTOK + o * 4);
            int w = 0;
            w = __builtin_amdgcn_cvt_pk_fp8_f32(v.x, v.y, w, false);
            w = __builtin_amdgcn_cvt_pk_fp8_f32(v.z, v.w, w, true);
            xsu[c * 128 + o] = (unsigned)w;
        }
    }

    __syncthreads();   // LDS tiles ready; below is wave-independent

    // ---- 3. build x B-fragment + token norm from the fp8 tile.
    // byte addr = c*512 + t: 4 lanes share a dword (broadcast), halves 2-way.
    long bf[8];
    float n2;
    const int t = wid * 32 + l5;               // token within block region
    {
        float s = 0.f;
        #pragma unroll
        for (int k = 0; k < 8; ++k) {
            const int c0 = k * 16 + hi * 8;
            unsigned lo = 0, hi32 = 0;
            #pragma unroll
            for (int j = 0; j < 4; ++j)
                lo |= (unsigned)xs8[(c0 + j) * 512 + t] << (8 * j);
            #pragma unroll
            for (int j = 0; j < 4; ++j)
                hi32 |= (unsigned)xs8[(c0 + 4 + j) * 512 + t] << (8 * j);
            bf[k] = (long)lo | ((long)hi32 << 32);
            f2 d0 = __builtin_amdgcn_cvt_pk_f32_fp8((int)lo, false);
            f2 d1 = __builtin_amdgcn_cvt_pk_f32_fp8((int)lo, true);
            f2 d2 = __builtin_amdgcn_cvt_pk_f32_fp8((int)hi32, false);
            f2 d3 = __builtin_amdgcn_cvt_pk_f32_fp8((int)hi32, true);
            s = fmaf(d0.x, d0.x, s); s = fmaf(d0.y, d0.y, s);
            s = fmaf(d1.x, d1.x, s); s = fmaf(d1.y, d1.y, s);
            s = fmaf(d2.x, d2.x, s); s = fmaf(d2.y, d2.y, s);
            s = fmaf(d3.x, d3.x, s); s = fmaf(d3.y, d3.y, s);
        }
        n2 = s + __shfl_xor(s, 32);            // halves hold half the channels
    }

    // ---- 4. hot loop: max-only over 512 rows, fp8 MFMA, A-frags from LDS
    float bmax = -1e30f;
    for (int mt = 0; mt < 16; ++mt) {
        long af[8];
        #pragma unroll
        for (int k = 0; k < 8; ++k)
            af[k] = sfrag[(mt * 8 + k) * 64 + lane];

        float16 acc;
        #pragma unroll
        for (int r = 0; r < 16; ++r) acc[r] = 0.f;
        #pragma unroll
        for (int k = 0; k < 8; ++k)
            acc = __builtin_amdgcn_mfma_f32_32x32x16_fp8_fp8(af[k], bf[k], acc, 0, 0, 0);

        float m0 = fmax3(acc[0], acc[1], acc[2]);
        float m1 = fmax3(acc[3], acc[4], acc[5]);
        float m2 = fmax3(acc[6], acc[7], acc[8]);
        float m3 = fmax3(acc[9], acc[10], acc[11]);
        float m4 = fmax3(acc[12], acc[13], acc[14]);
        bmax = fmaxf(bmax, fmax3(fmax3(m0, m1, m2), fmax3(m3, m4, acc[15]), bmax));
    }

    // ---- threshold: bv/||x|| > 0.8  <=>  bv > 0.8*||x|| (norm > 0)
    bmax = fmaxf(bmax, __shfl_xor(bmax, 32));   // merge hi-half rows
    const bool msk = bmax > 0.8f * fmaxf(sqrtf(n2), 1e-12f);

    const unsigned long long wb = __ballot(msk);
    if (wb == 0ULL) return;   // common case: zeros already written by fill

    // ---- rare path: exact argmax recompute (identical MFMAs), overwrite hits
    float bestv = -1e30f; int besti = 0;
    for (int mt = 0; mt < 16; ++mt) {
        long af[8];
        #pragma unroll
        for (int k = 0; k < 8; ++k)
            af[k] = sfrag[(mt * 8 + k) * 64 + lane];
        float16 acc;
        #pragma unroll
        for (int r = 0; r < 16; ++r) acc[r] = 0.f;
        #pragma unroll
        for (int k = 0; k < 8; ++k)
            acc = __builtin_amdgcn_mfma_f32_32x32x16_fp8_fp8(af[k], bf[k], acc, 0, 0, 0);
        const int rbase = mt * 32 + 4 * hi;
        #pragma unroll
        for (int r = 0; r < 16; ++r) {
            // C/D map (shape-determined): row=(reg&3)+8*(reg>>2)+4*(lane>>5)
            const int row = rbase + (r & 3) + 8 * (r >> 2);
            if (acc[r] > bestv) { bestv = acc[r]; besti = row; }
        }
    }
    float ov = __shfl_xor(bestv, 32);
    int   oi = __shfl_xor(besti, 32);
    if (ov > bestv || (ov == bestv && oi < besti)) { bestv = ov; besti = oi; }

    if (msk) {   // overwrite ONLY hit tokens (zeros elsewhere pre-filled)
        const int tt = treg + t;
        const float* mrow = mem + (size_t)besti * CCH;
        #pragma unroll 8
        for (int k = 0; k < 64; ++k) {
            int c = hi + 2 * k;
            obase[(size_t)c * HWTOK + tt] = mrow[c];
        }
    }
}

// ---------------------------------------------------------------------------
extern "C" void kernel_launch(void* const* d_in, const int* in_sizes, int n_in,
                              void* d_out, int out_size, void* d_ws, size_t ws_size,
                              hipStream_t stream) {
    const float* x   = (const float*)d_in[0];   // [32,128,64,64]
    const float* mem = (const float*)d_in[1];   // [512,128]
    float* out       = (float*)d_out;
    long* wsfrag     = (long*)d_ws;             // 64 KB fp8 fragment workspace

    frag_kernel<<<32, 256, 0, stream>>>(mem, wsfrag);
    fill_kernel<<<2048, 256, 0, stream>>>(out);
    hardmem_mfma<<<256, THREADS, 0, stream>>>(x, mem, wsfrag, out);
}